// Round 8
// baseline (7288.798 us; speedup 1.0000x reference)
//
#include <hip/hip_runtime.h>
#include <hip/hip_cooperative_groups.h>
#include <math.h>

namespace cg = cooperative_groups;

#define Bp 64
#define Sp 512
#define Ep 128
#define Hp 1024
#define Vp 128
#define Op 128
#define BH (Bp * Hp)

typedef short s8v __attribute__((ext_vector_type(8)));
typedef float f4v __attribute__((ext_vector_type(4)));

// ws layout (float units):
//   XV   : Vp*3*Hp floats        x-side projections per vocab id (incl. input biases)
//   Whi  : 3*Hp*Hp ushort        scan bf16 hi weights, row = ((j>>4)*3+g)*16+(j&15), k-contig
//   Wlo  : 3*Hp*Hp ushort        scan bf16 lo residuals, same layout
//   ysH  : (Sp+1)*BH ushort      bf16 hi of h history; row 0 = h_init, row t+1 = h_t
//   hloP : 2*BH ushort           bf16 lo of h, ping-pong (recurrence accuracy only)
//   WhbH/WhbL : Hp*Hp ushort     dense Wh bf16 hi/lo, [n][k] k-contig
//   WobH/WobL : Op*Hp ushort     dense Wo bf16 hi/lo, [o][k] k-contig
//   flg  : 1024 uints            flags[mb][jb]: flags[mb*64+jb] = t+1 (256B/row)
#define WS_XV    0
#define WS_WHI   (WS_XV + Vp*3*Hp)
#define WS_WLO   (WS_WHI + (3*Hp*Hp)/2)
#define WS_YSH   (WS_WLO + (3*Hp*Hp)/2)
#define WS_HLOP  (WS_YSH + ((size_t)(Sp+1)*BH)/2)
#define WS_WHBH  (WS_HLOP + (2*BH)/2)
#define WS_WHBL  (WS_WHBH + (Hp*Hp)/2)
#define WS_WOBH  (WS_WHBL + (Hp*Hp)/2)
#define WS_WOBL  (WS_WOBH + (Op*Hp)/2)
#define WS_FLG   (WS_WOBL + (Op*Hp)/2)
#define WS_FLOATS (WS_FLG + 1024)

__device__ __forceinline__ unsigned short f2bf(float x) {
  union { float f; unsigned u; } v; v.f = x;
  unsigned r = v.u + 0x7fffu + ((v.u >> 16) & 1u);   // RNE
  return (unsigned short)(r >> 16);
}
__device__ __forceinline__ float bf2f(unsigned short h) {
  union { unsigned u; float f; } v; v.u = ((unsigned)h) << 16;
  return v.f;
}

// agent-coherent 16B load as two 8B relaxed atomics (sc1 — reads the coherence
// point; immune to stale per-XCD L2)
__device__ __forceinline__ s8v ald16(const unsigned short* p) {
  union { unsigned long long q[2]; s8v v; } u;
  const unsigned long long* qp = (const unsigned long long*)p;
  u.q[0] = __hip_atomic_load(qp,     __ATOMIC_RELAXED, __HIP_MEMORY_SCOPE_AGENT);
  u.q[1] = __hip_atomic_load(qp + 1, __ATOMIC_RELAXED, __HIP_MEMORY_SCOPE_AGENT);
  return u.v;
}
__device__ __forceinline__ void ast8(unsigned short* p, unsigned long long v) {
  __hip_atomic_store((unsigned long long*)p, v, __ATOMIC_RELAXED, __HIP_MEMORY_SCOPE_AGENT);
}

// ---------------------------------------------------------------- XV precompute
__global__ __launch_bounds__(256) void xv_kernel(
    const float* __restrict__ emb,
    const float* __restrict__ Wir, const float* __restrict__ bir,
    const float* __restrict__ Wiz, const float* __restrict__ biz,
    const float* __restrict__ Win, const float* __restrict__ bin_,
    float* __restrict__ XV) {
  int n = blockIdx.x * 256 + threadIdx.x;   // 0..3071
  int v = blockIdx.y;                        // 0..127
  int g = n >> 10;
  int j = n & (Hp - 1);
  const float* W = (g == 0) ? Wir : ((g == 1) ? Wiz : Win);
  const float* bias = (g == 0) ? bir : ((g == 1) ? biz : bin_);
  float acc = bias[j];
  const float* ev = emb + (size_t)v * Ep;
  for (int e = 0; e < Ep; ++e) acc += ev[e] * W[(size_t)e * Hp + j];
  XV[(size_t)v * (3 * Hp) + n] = acc;
}

// ---------------------------------------------------------------- scan weight pack (bf16 hi/lo)
__global__ void wpack_kernel(const float* __restrict__ Whr,
                             const float* __restrict__ Whz,
                             const float* __restrict__ Whn,
                             unsigned short* __restrict__ Whi,
                             unsigned short* __restrict__ Wlo) {
  __shared__ float tile[32][33];
  int g = blockIdx.z;
  const float* src = (g == 0) ? Whr : ((g == 1) ? Whz : Whn);
  int kb = blockIdx.x * 32;
  int jb32 = blockIdx.y * 32;
  int tx = threadIdx.x, ty = threadIdx.y;  // 32 x 8
  #pragma unroll
  for (int i = 0; i < 4; ++i)
    tile[ty + 8 * i][tx] = src[(size_t)(kb + ty + 8 * i) * Hp + (jb32 + tx)];
  __syncthreads();
  #pragma unroll
  for (int i = 0; i < 4; ++i) {
    int jl = ty + 8 * i;
    int j = jb32 + jl;
    int dstRow = ((j >> 4) * 3 + g) * 16 + (j & 15);
    float w = tile[tx][jl];
    unsigned short hi = f2bf(w);
    Whi[(size_t)dstRow * Hp + kb + tx] = hi;
    Wlo[(size_t)dstRow * Hp + kb + tx] = f2bf(w - bf2f(hi));
  }
}

// ---------------------------------------------------------------- generic transpose+split
// src [K][N] fp32 -> dhi/dlo [N][K] bf16
__global__ void tsplit_kernel(const float* __restrict__ src, int K, int N,
                              unsigned short* __restrict__ dhi,
                              unsigned short* __restrict__ dlo) {
  __shared__ float tile[32][33];
  int kb = blockIdx.x * 32, nb = blockIdx.y * 32;
  int tx = threadIdx.x, ty = threadIdx.y;  // 32 x 8
  #pragma unroll
  for (int i = 0; i < 4; ++i)
    tile[ty + 8 * i][tx] = src[(size_t)(kb + ty + 8 * i) * N + nb + tx];
  __syncthreads();
  #pragma unroll
  for (int i = 0; i < 4; ++i) {
    int nl = ty + 8 * i;
    float w = tile[tx][nl];
    unsigned short hi = f2bf(w);
    dhi[(size_t)(nb + nl) * K + kb + tx] = hi;
    dlo[(size_t)(nb + nl) * K + kb + tx] = f2bf(w - bf2f(hi));
  }
}

// ---------------------------------------------------------------- h0 -> bf16 hi/lo ; zero flags
__global__ void h0_kernel(const float* __restrict__ carry,
                          unsigned short* __restrict__ ysH,
                          unsigned short* __restrict__ hloP,
                          unsigned* __restrict__ flg) {
  int i = blockIdx.x * 256 + threadIdx.x;
  float h = carry[i];
  unsigned short hi = f2bf(h);
  ysH[i] = hi;                    // row 0 of history
  hloP[i] = f2bf(h - bf2f(hi));   // slot 0
  if (i < 1024) flg[i] = 0u;
}

// ---------------------------------------------------------------- persistent MFMA GRU scan
// 128 blocks x 256 threads. jb = blk>>1 (16 cols), mp = blk&1.
// Block INTERLEAVES two independent recurrences mb = {2mp, 2mp+1}: while one
// group's h-exchange round-trips through L3, it computes the other.
// Sync = flag array: producer stores flags[mb][jb]=t+1 (contention-free),
// consumer polls all 64 flags with one coalesced 64-lane load + __all.
// No cache-wide fences anywhere; h planes + flags use agent-scope relaxed
// atomics (sc1), weights/XV/tokens stay normal cached loads (L2-warm).
__global__ __launch_bounds__(256, 1) void gru_scan(
    const float* __restrict__ carry,
    unsigned short* ysH,
    const unsigned short* __restrict__ Whi,
    const unsigned short* __restrict__ Wlo,
    const float* __restrict__ XV,
    const int* __restrict__ toks,
    const float* __restrict__ bhn,
    unsigned short* hloP,
    unsigned* flg) {
  __shared__ float part[3 * 4 * 64 * 4];    // [g][wave][lane][reg] = 12 KB
  __shared__ unsigned short hst[2][16][16]; // staged h tile (hi, lo), 1 KB

  const int tid = threadIdx.x;
  const int wv = tid >> 6, lane = tid & 63;
  const int jb = blockIdx.x >> 1, mp = blockIdx.x & 1;
  const int col = lane & 15, kq = lane >> 4;

  const int kbase = wv * 256 + kq * 8;
  const unsigned short* bhp[3];
  const unsigned short* blp[3];
  #pragma unroll
  for (int g = 0; g < 3; ++g) {
    const size_t rowoff = ((size_t)(jb * 3 + g) * 16 + col) * Hp + kbase;
    bhp[g] = Whi + rowoff;
    blp[g] = Wlo + rowoff;
  }

  // epilogue mapping: thread -> one output element (16x16 tile)
  const int erow = tid >> 4, ecol = tid & 15;
  const int ej = jb * 16 + ecol;
  const int elane = (erow >> 2) * 16 + ecol;
  const int er = erow & 3;
  const float bhnv = bhn[ej];

  // store mapping: threads 0..127 -> one 8-B chunk (plane, row, quad)
  const int splane = tid >> 6;
  const int srow = (tid >> 2) & 15;
  const int squad = tid & 3;

  // per-recurrence (i = 0,1 -> mb = 2mp+i) persistent state
  int mbA[2];
  int ebA[2];
  size_t aBase[2], eOff[2], sOff[2];
  float holdR[2], xr[2], xz[2], xn[2];
  #pragma unroll
  for (int i = 0; i < 2; ++i) {
    int mb = 2 * mp + i;
    mbA[i] = mb;
    ebA[i] = mb * 16 + erow;
    aBase[i] = (size_t)(mb * 16 + col) * Hp + kbase;
    eOff[i] = (size_t)ebA[i] * Hp + ej;
    sOff[i] = (size_t)(mb * 16 + srow) * Hp + jb * 16 + squad * 4;
    holdR[i] = carry[eOff[i]];
    int tok0 = toks[ebA[i] * Sp + 0];
    const float* xvp0 = XV + (size_t)tok0 * (3 * Hp) + ej;
    xr[i] = xvp0[0]; xz[i] = xvp0[Hp]; xn[i] = xvp0[2 * Hp];
  }

  for (int t = 0; t < Sp; ++t) {
    const unsigned short* hhiR = ysH + (size_t)t * BH;
    const unsigned short* hloR = hloP + (size_t)(t & 1) * BH;
    unsigned short* hhiW = ysH + (size_t)(t + 1) * BH;
    unsigned short* hloW = hloP + (size_t)((t + 1) & 1) * BH;

    for (int i = 0; i < 2; ++i) {
      const int mb = mbA[i];

      // ---- wait for h(t-1) of this group: coalesced 64-flag poll ----
      if (t > 0) {
        const unsigned* fp = flg + mb * 64 + lane;
        while (true) {
          unsigned f = __hip_atomic_load(fp, __ATOMIC_RELAXED, __HIP_MEMORY_SCOPE_AGENT);
          if (__all((int)(f >= (unsigned)t))) break;
          __builtin_amdgcn_s_sleep(1);
        }
      }

      // A fragments (agent-coherent; the only barrier-dependent loads)
      s8v ah[8], al[8];
      #pragma unroll
      for (int c = 0; c < 8; ++c) {
        ah[c] = ald16(hhiR + aBase[i] + (size_t)c * 32);
        al[c] = ald16(hloR + aBase[i] + (size_t)c * 32);
      }

      // prefetch next step's token + XV gate values (independent of h)
      float xrN, xzN, xnN;
      {
        int tN = (t + 1 < Sp) ? (t + 1) : t;
        int tokN = toks[ebA[i] * Sp + tN];
        const float* xvpN = XV + (size_t)tokN * (3 * Hp) + ej;
        xrN = xvpN[0];
        xzN = xvpN[Hp];
        xnN = xvpN[2 * Hp];
      }

      f4v ar = {0.f, 0.f, 0.f, 0.f}, az = {0.f, 0.f, 0.f, 0.f}, an = {0.f, 0.f, 0.f, 0.f};
      #pragma unroll
      for (int c = 0; c < 8; ++c) {
        s8v b0 = *(const s8v*)(bhp[0] + c * 32);
        s8v b1 = *(const s8v*)(bhp[1] + c * 32);
        s8v b2 = *(const s8v*)(bhp[2] + c * 32);
        s8v l0 = *(const s8v*)(blp[0] + c * 32);
        s8v l1 = *(const s8v*)(blp[1] + c * 32);
        s8v l2 = *(const s8v*)(blp[2] + c * 32);
        ar = __builtin_amdgcn_mfma_f32_16x16x32_bf16(ah[c], b0, ar, 0, 0, 0);
        az = __builtin_amdgcn_mfma_f32_16x16x32_bf16(ah[c], b1, az, 0, 0, 0);
        an = __builtin_amdgcn_mfma_f32_16x16x32_bf16(ah[c], b2, an, 0, 0, 0);
        ar = __builtin_amdgcn_mfma_f32_16x16x32_bf16(al[c], b0, ar, 0, 0, 0);
        az = __builtin_amdgcn_mfma_f32_16x16x32_bf16(al[c], b1, az, 0, 0, 0);
        an = __builtin_amdgcn_mfma_f32_16x16x32_bf16(al[c], b2, an, 0, 0, 0);
        ar = __builtin_amdgcn_mfma_f32_16x16x32_bf16(ah[c], l0, ar, 0, 0, 0);
        az = __builtin_amdgcn_mfma_f32_16x16x32_bf16(ah[c], l1, az, 0, 0, 0);
        an = __builtin_amdgcn_mfma_f32_16x16x32_bf16(ah[c], l2, an, 0, 0, 0);
      }

      // cross-wave K reduction via LDS
      *(f4v*)&part[((0 * 4 + wv) * 64 + lane) * 4] = ar;
      *(f4v*)&part[((1 * 4 + wv) * 64 + lane) * 4] = az;
      *(f4v*)&part[((2 * 4 + wv) * 64 + lane) * 4] = an;
      __syncthreads();

      float sr = 0.f, sz = 0.f, sn = 0.f;
      #pragma unroll
      for (int w = 0; w < 4; ++w) {
        sr += part[((0 * 4 + w) * 64 + elane) * 4 + er];
        sz += part[((1 * 4 + w) * 64 + elane) * 4 + er];
        sn += part[((2 * 4 + w) * 64 + elane) * 4 + er];
      }

      float rg = 1.f / (1.f + expf(-(sr + xr[i])));
      float zg = 1.f / (1.f + expf(-(sz + xz[i])));
      float ng = tanhf(xn[i] + rg * (sn + bhnv));
      float hnew = (1.f - zg) * ng + zg * holdR[i];

      unsigned short hi16 = f2bf(hnew);
      hst[0][erow][ecol] = hi16;
      hst[1][erow][ecol] = f2bf(hnew - bf2f(hi16));

      holdR[i] = hnew;
      xr[i] = xrN; xz[i] = xzN; xn[i] = xnN;

      __syncthreads();
      // vectorized agent-coherent h stores (threads 0..127, 8 B each)
      if (tid < 128) {
        unsigned long long v = *(const unsigned long long*)&hst[splane][srow][squad * 4];
        ast8((splane ? hloW : hhiW) + sOff[i], v);
      }

      // drain stores (each thread waits its own vmcnt), then publish flag
      __threadfence_block();
      __syncthreads();
      if (tid == 0)
        __hip_atomic_store(flg + mb * 64 + jb, (unsigned)(t + 1),
                           __ATOMIC_RELAXED, __HIP_MEMORY_SCOPE_AGENT);
    }
  }
}

// ---------------------------------------------------------------- fused MFMA output denses
// block = 16 out rows (r = b*S + s), 4 waves. Pass1: hidden = h@Wh+bh with
// B hi/lo (weight-exact); hidden tile -> LDS (MFMA-A layout, bf16). Pass2:
// logits = hidden@Wo+bo. Hidden never touches HBM.
__global__ __launch_bounds__(256, 1) void dense_kernel(
    const unsigned short* __restrict__ ysH,   // [(S+1)][B][H] bf16 hi; rows 1..S = h_t
    const unsigned short* __restrict__ WhbH, const unsigned short* __restrict__ WhbL,
    const float* __restrict__ bh,
    const unsigned short* __restrict__ WobH, const unsigned short* __restrict__ WobL,
    const float* __restrict__ bo,
    float* __restrict__ out) {
  __shared__ unsigned short aHi[32 * 16 * 4 * 8];    // [kc][m][kq][8] = 32 KB
  __shared__ unsigned short hidBf[32 * 16 * 4 * 8];  // same layout, 32 KB

  const int tid = threadIdx.x;
  const int wv = tid >> 6, lane = tid & 63;
  const int col = lane & 15, kq = lane >> 4;
  const int r0 = blockIdx.x * 16;
  const int bq = r0 / Sp, s0 = r0 % Sp;   // S%16==0: bq constant in tile

  // stage A: 16 rows x 1024 bf16, re-laid for conflict-free frag reads
  for (int i = tid; i < 16 * 128; i += 256) {
    int m = i >> 7, c8 = i & 127;          // chunk of 8 shorts, k = c8*8
    int kc = c8 >> 2, kqi = c8 & 3;
    const uint4* src = (const uint4*)(ysH + ((size_t)(s0 + m + 1) * Bp + bq) * Hp) + c8;
    *(uint4*)&aHi[((kc * 16 + m) * 4 + kqi) * 8] = *src;
  }
  __syncthreads();

  // ---- pass 1: wave w covers n in [w*256, w*256+256) ----
  f4v acc[16];
  #pragma unroll
  for (int nt = 0; nt < 16; ++nt) acc[nt] = (f4v){0.f, 0.f, 0.f, 0.f};
  for (int kc = 0; kc < 32; ++kc) {
    s8v a = *(const s8v*)&aHi[(kc * 64 + col * 4 + kq) * 8];
    const size_t koff = (size_t)kc * 32 + kq * 8;
    #pragma unroll
    for (int nt = 0; nt < 16; ++nt) {
      int n = wv * 256 + nt * 16 + col;
      s8v bHi = *(const s8v*)(WhbH + (size_t)n * Hp + koff);
      s8v bLo = *(const s8v*)(WhbL + (size_t)n * Hp + koff);
      acc[nt] = __builtin_amdgcn_mfma_f32_16x16x32_bf16(a, bHi, acc[nt], 0, 0, 0);
      acc[nt] = __builtin_amdgcn_mfma_f32_16x16x32_bf16(a, bLo, acc[nt], 0, 0, 0);
    }
  }
  // epilogue: +bias, bf16, scatter into MFMA-A layout (k = hidden feature n)
  #pragma unroll
  for (int nt = 0; nt < 16; ++nt) {
    int n = wv * 256 + nt * 16 + col;
    float bias = bh[n];
    int kc = n >> 5, kqi = (n >> 3) & 3, ii = n & 7;
    #pragma unroll
    for (int r = 0; r < 4; ++r) {
      int m = kq * 4 + r;                  // C-layout: row = (lane>>4)*4 + reg
      hidBf[((kc * 16 + m) * 4 + kqi) * 8 + ii] = f2bf(acc[nt][r] + bias);
    }
  }
  __syncthreads();

  // ---- pass 2: wave w covers o-tiles {2w, 2w+1} ----
  f4v lacc[2];
  lacc[0] = (f4v){0.f, 0.f, 0.f, 0.f};
  lacc[1] = (f4v){0.f, 0.f, 0.f, 0.f};
  for (int kc = 0; kc < 32; ++kc) {
    s8v a = *(const s8v*)&hidBf[(kc * 64 + col * 4 + kq) * 8];
    const size_t koff = (size_t)kc * 32 + kq * 8;
    #pragma unroll
    for (int ot = 0; ot < 2; ++ot) {
      int o = (wv * 2 + ot) * 16 + col;
      s8v bHi = *(const s8v*)(WobH + (size_t)o * Hp + koff);
      s8v bLo = *(const s8v*)(WobL + (size_t)o * Hp + koff);
      lacc[ot] = __builtin_amdgcn_mfma_f32_16x16x32_bf16(a, bHi, lacc[ot], 0, 0, 0);
      lacc[ot] = __builtin_amdgcn_mfma_f32_16x16x32_bf16(a, bLo, lacc[ot], 0, 0, 0);
    }
  }
  float* lo = out + (size_t)Bp * Hp;
  #pragma unroll
  for (int ot = 0; ot < 2; ++ot) {
    int o = (wv * 2 + ot) * 16 + col;
    float bias = bo[o];
    #pragma unroll
    for (int r = 0; r < 4; ++r) {
      int m = kq * 4 + r;
      lo[(size_t)(r0 + m) * Op + o] = lacc[ot][r] + bias;
    }
  }
}

// ---------------------------------------------------------------- carry out (hi+lo reconstruct)
__global__ void carry_kernel(const unsigned short* __restrict__ ysH,
                             const unsigned short* __restrict__ hloP,
                             float* __restrict__ out) {
  int i = blockIdx.x * 256 + threadIdx.x;
  out[i] = bf2f(ysH[(size_t)Sp * BH + i]) + bf2f(hloP[(size_t)(Sp & 1) * BH + i]);
}

extern "C" void kernel_launch(void* const* d_in, const int* in_sizes, int n_in,
                              void* d_out, int out_size, void* d_ws, size_t ws_size,
                              hipStream_t stream) {
  const int*   toks = (const int*)  d_in[0];
  const float* carry= (const float*)d_in[1];
  const float* emb  = (const float*)d_in[2];
  const float* Wir  = (const float*)d_in[3];
  const float* bir  = (const float*)d_in[4];
  const float* Whr  = (const float*)d_in[5];
  const float* Wiz  = (const float*)d_in[6];
  const float* biz  = (const float*)d_in[7];
  const float* Whz  = (const float*)d_in[8];
  const float* Win  = (const float*)d_in[9];
  const float* bin_ = (const float*)d_in[10];
  const float* Whn  = (const float*)d_in[11];
  const float* bhn  = (const float*)d_in[12];
  const float* Wh   = (const float*)d_in[13];
  const float* bh   = (const float*)d_in[14];
  const float* Wo   = (const float*)d_in[15];
  const float* bo   = (const float*)d_in[16];
  float* out = (float*)d_out;

  if (ws_size < WS_FLOATS * sizeof(float)) return;

  float* ws = (float*)d_ws;
  float* XV = ws + WS_XV;
  unsigned short* WhiP = (unsigned short*)(ws + WS_WHI);
  unsigned short* WloP = (unsigned short*)(ws + WS_WLO);
  unsigned short* ysH  = (unsigned short*)(ws + WS_YSH);
  unsigned short* hloP = (unsigned short*)(ws + WS_HLOP);
  unsigned short* WhbH = (unsigned short*)(ws + WS_WHBH);
  unsigned short* WhbL = (unsigned short*)(ws + WS_WHBL);
  unsigned short* WobH = (unsigned short*)(ws + WS_WOBH);
  unsigned short* WobL = (unsigned short*)(ws + WS_WOBL);
  unsigned* flg = (unsigned*)(ws + WS_FLG);

  // preps
  xv_kernel<<<dim3(12, Vp), 256, 0, stream>>>(emb, Wir, bir, Wiz, biz, Win, bin_, XV);
  wpack_kernel<<<dim3(Hp / 32, Hp / 32, 3), dim3(32, 8), 0, stream>>>(Whr, Whz, Whn, WhiP, WloP);
  tsplit_kernel<<<dim3(Hp / 32, Hp / 32), dim3(32, 8), 0, stream>>>(Wh, Hp, Hp, WhbH, WhbL);
  tsplit_kernel<<<dim3(Hp / 32, Op / 32), dim3(32, 8), 0, stream>>>(Wo, Hp, Op, WobH, WobL);
  h0_kernel<<<BH / 256, 256, 0, stream>>>(carry, ysH, hloP, flg);

  // persistent cooperative MFMA scan (128 blocks, 2-way recurrence interleave)
  {
    void* args[] = {(void*)&carry, (void*)&ysH, (void*)&WhiP, (void*)&WloP,
                    (void*)&XV, (void*)&toks, (void*)&bhn,
                    (void*)&hloP, (void*)&flg};
    hipLaunchCooperativeKernel((const void*)gru_scan, dim3(128), dim3(256),
                               args, 0, stream);
  }

  // outputs
  carry_kernel<<<BH / 256, 256, 0, stream>>>(ysH, hloP, out);
  dense_kernel<<<(Bp * Sp) / 16, 256, 0, stream>>>(ysH, WhbH, WhbL, bh, WobH, WobL, bo, out);
}

// Round 10
// 5048.539 us; speedup vs baseline: 1.4437x; 1.4437x over previous
//
#include <hip/hip_runtime.h>
#include <math.h>

#define Bp 64
#define Sp 512
#define Ep 128
#define Hp 1024
#define Vp 128
#define Op 128
#define BH (Bp * Hp)

typedef short s8v __attribute__((ext_vector_type(8)));
typedef float f4v __attribute__((ext_vector_type(4)));

// ws layout (float units):
//   XV   : Vp*3*Hp floats      x-side projections per vocab id (incl. input biases)
//   Whi  : 3*Hp*Hp ushort      scan bf16 hi weights, row = ((j>>4)*3+g)*16+(j&15), k-contig
//   Wlo  : 3*Hp*Hp ushort      scan bf16 lo residuals, same layout
//   ysH  : (Sp+1)*BH ushort    bf16 hi of h history; row t+1 = h_t (dense/carry input)
//   hx   : 2*(BH/2) ulongs     self-validating h exchange ping-pong:
//                              record = [hi(j),lo(j),hi(j+1),lo(j+1)], lo 2 LSBs = tag (t&3)
//   WhbH/WhbL : Hp*Hp ushort   dense Wh bf16 hi/lo, [n][k] k-contig
//   WobH/WobL : Op*Hp ushort   dense Wo bf16 hi/lo, [o][k] k-contig
#define WS_XV    0
#define WS_WHI   (WS_XV + Vp*3*Hp)
#define WS_WLO   (WS_WHI + (3*Hp*Hp)/2)
#define WS_YSH   (WS_WLO + (3*Hp*Hp)/2)
#define WS_HX    (WS_YSH + ((size_t)(Sp+1)*BH)/2)
#define WS_WHBH  (WS_HX + 2*(BH/2)*2)          /* 2 slots * BH/2 ulongs * 2 floats/ulong */
#define WS_WHBL  (WS_WHBH + (Hp*Hp)/2)
#define WS_WOBH  (WS_WHBL + (Hp*Hp)/2)
#define WS_WOBL  (WS_WOBH + (Op*Hp)/2)
#define WS_FLOATS (WS_WOBL + (Op*Hp)/2)

__device__ __forceinline__ unsigned short f2bf(float x) {
  union { float f; unsigned u; } v; v.f = x;
  unsigned r = v.u + 0x7fffu + ((v.u >> 16) & 1u);   // RNE
  return (unsigned short)(r >> 16);
}
__device__ __forceinline__ float bf2f(unsigned short h) {
  union { unsigned u; float f; } v; v.u = ((unsigned)h) << 16;
  return v.f;
}

// ---------------------------------------------------------------- XV precompute
__global__ __launch_bounds__(256) void xv_kernel(
    const float* __restrict__ emb,
    const float* __restrict__ Wir, const float* __restrict__ bir,
    const float* __restrict__ Wiz, const float* __restrict__ biz,
    const float* __restrict__ Win, const float* __restrict__ bin_,
    float* __restrict__ XV) {
  int n = blockIdx.x * 256 + threadIdx.x;   // 0..3071
  int v = blockIdx.y;                        // 0..127
  int g = n >> 10;
  int j = n & (Hp - 1);
  const float* W = (g == 0) ? Wir : ((g == 1) ? Wiz : Win);
  const float* bias = (g == 0) ? bir : ((g == 1) ? biz : bin_);
  float acc = bias[j];
  const float* ev = emb + (size_t)v * Ep;
  for (int e = 0; e < Ep; ++e) acc += ev[e] * W[(size_t)e * Hp + j];
  XV[(size_t)v * (3 * Hp) + n] = acc;
}

// ---------------------------------------------------------------- scan weight pack (bf16 hi/lo)
__global__ void wpack_kernel(const float* __restrict__ Whr,
                             const float* __restrict__ Whz,
                             const float* __restrict__ Whn,
                             unsigned short* __restrict__ Whi,
                             unsigned short* __restrict__ Wlo) {
  __shared__ float tile[32][33];
  int g = blockIdx.z;
  const float* src = (g == 0) ? Whr : ((g == 1) ? Whz : Whn);
  int kb = blockIdx.x * 32;
  int jb32 = blockIdx.y * 32;
  int tx = threadIdx.x, ty = threadIdx.y;  // 32 x 8
  #pragma unroll
  for (int i = 0; i < 4; ++i)
    tile[ty + 8 * i][tx] = src[(size_t)(kb + ty + 8 * i) * Hp + (jb32 + tx)];
  __syncthreads();
  #pragma unroll
  for (int i = 0; i < 4; ++i) {
    int jl = ty + 8 * i;
    int j = jb32 + jl;
    int dstRow = ((j >> 4) * 3 + g) * 16 + (j & 15);
    float w = tile[tx][jl];
    unsigned short hi = f2bf(w);
    Whi[(size_t)dstRow * Hp + kb + tx] = hi;
    Wlo[(size_t)dstRow * Hp + kb + tx] = f2bf(w - bf2f(hi));
  }
}

// ---------------------------------------------------------------- generic transpose+split
__global__ void tsplit_kernel(const float* __restrict__ src, int K, int N,
                              unsigned short* __restrict__ dhi,
                              unsigned short* __restrict__ dlo) {
  __shared__ float tile[32][33];
  int kb = blockIdx.x * 32, nb = blockIdx.y * 32;
  int tx = threadIdx.x, ty = threadIdx.y;  // 32 x 8
  #pragma unroll
  for (int i = 0; i < 4; ++i)
    tile[ty + 8 * i][tx] = src[(size_t)(kb + ty + 8 * i) * N + nb + tx];
  __syncthreads();
  #pragma unroll
  for (int i = 0; i < 4; ++i) {
    int nl = ty + 8 * i;
    float w = tile[tx][nl];
    unsigned short hi = f2bf(w);
    dhi[(size_t)(nb + nl) * K + kb + tx] = hi;
    dlo[(size_t)(nb + nl) * K + kb + tx] = f2bf(w - bf2f(hi));
  }
}

// ---------------------------------------------------------------- h_init -> exchange records
// h_{-1} lives in hx slot 1 with tag 3 (= (-1)&3).
__global__ void h0_kernel(const float* __restrict__ carry,
                          unsigned long long* __restrict__ hx) {
  int i = blockIdx.x * 256 + threadIdx.x;   // record index, 0..BH/2
  int b = i >> 9, jp = i & 511;
  float f0 = carry[(size_t)b * Hp + 2 * jp];
  float f1 = carry[(size_t)b * Hp + 2 * jp + 1];
  unsigned long long h0 = f2bf(f0);
  unsigned long long l0 = (f2bf(f0 - bf2f((unsigned short)h0)) & 0xFFFCu) | 3u;
  unsigned long long h1 = f2bf(f1);
  unsigned long long l1 = (f2bf(f1 - bf2f((unsigned short)h1)) & 0xFFFCu) | 3u;
  unsigned long long rec = h0 | (l0 << 16) | (h1 << 32) | (l1 << 48);
  __hip_atomic_store(hx + (BH / 2) + i, rec, __ATOMIC_RELAXED, __HIP_MEMORY_SCOPE_AGENT);
}

// ---------------------------------------------------------------- persistent MFMA GRU scan
// 256 blocks x 256 threads, PLAIN launch (no cooperative API). Co-residency is
// guaranteed by capacity: __launch_bounds__(256,1) caps VGPR at 512/wave so
// every CU hosts >=1 block; 256 blocks always fit. Dataflow (tag-validated
// records) is the only synchronization -> any dispatch order is correct.
// mb = blk&3 (16-batch group), jb = blk>>2 (16 cols). No barriers, no fences.
__global__ __launch_bounds__(256, 1) void gru_scan(
    const float* __restrict__ carry,
    unsigned short* __restrict__ ysH,
    const unsigned short* __restrict__ Whi,
    const unsigned short* __restrict__ Wlo,
    const float* __restrict__ XV,
    const int* __restrict__ toks,
    const float* __restrict__ bhn,
    unsigned long long* hx) {
  __shared__ float part[3 * 4 * 64 * 4];    // [g][wave][lane][reg] = 12 KB
  __shared__ unsigned short hst[2][16][16]; // staged h tile (hi, lo), 1 KB

  const int tid = threadIdx.x;
  const int wv = tid >> 6, lane = tid & 63;
  const int mb = blockIdx.x & 3, jb = blockIdx.x >> 2;
  const int col = lane & 15, kq = lane >> 4;

  const int kbase = wv * 256 + kq * 8;
  const unsigned short* bhp[3];
  const unsigned short* blp[3];
  #pragma unroll
  for (int g = 0; g < 3; ++g) {
    const size_t rowoff = ((size_t)(jb * 3 + g) * 16 + col) * Hp + kbase;
    bhp[g] = Whi + rowoff;
    blp[g] = Wlo + rowoff;
  }

  // epilogue mapping: thread -> one output element (16x16 tile)
  const int erow = tid >> 4, ecol = tid & 15;
  const int eb = mb * 16 + erow;
  const int ej = jb * 16 + ecol;
  const int elane = (erow >> 2) * 16 + ecol;
  const int er = erow & 3;
  const float bhnv = bhn[ej];

  const size_t eOff = (size_t)eb * Hp + ej;
  // A-record base for this lane: row b = mb*16+col, records for cols
  // kbase + c*32 + [0,8) -> 4 ulongs at b*512 + wv*128 + c*16 + kq*4
  const size_t rBase = (size_t)(mb * 16 + col) * 512 + wv * 128 + kq * 4;

  float holdR = carry[eOff];
  int tok0 = toks[eb * Sp + 0];
  const float* xvp0 = XV + (size_t)tok0 * (3 * Hp) + ej;
  float xr = xvp0[0], xz = xvp0[Hp], xn = xvp0[2 * Hp];

  for (int t = 0; t < Sp; ++t) {
    const unsigned long long* hxR = hx + (size_t)((t + 1) & 1) * (BH / 2);
    unsigned long long* hxW = hx + (size_t)(t & 1) * (BH / 2);
    const unsigned tagR = (unsigned)((t + 3) & 3);
    const unsigned long long Mv = (0x3ULL << 16) | (0x3ULL << 48);
    const unsigned long long Ev = ((unsigned long long)tagR << 16) |
                                  ((unsigned long long)tagR << 48);

    // ---- validated A-record load + inline unpack (retry until all tags match)
    // unpack per-chunk keeps register pressure low (no d[8][4] array).
    s8v ah[8], al[8];
    while (true) {
      int ok = 1;
      #pragma unroll
      for (int c = 0; c < 8; ++c) {
        union { unsigned u[4]; s8v v; } H, L;
        #pragma unroll
        for (int rr = 0; rr < 4; ++rr) {
          unsigned long long q = __hip_atomic_load(hxR + rBase + c * 16 + rr,
                                     __ATOMIC_RELAXED, __HIP_MEMORY_SCOPE_AGENT);
          ok &= ((q & Mv) == Ev) ? 1 : 0;
          unsigned lo32 = (unsigned)q;
          unsigned hi32 = (unsigned)(q >> 32);
          H.u[rr] = __builtin_amdgcn_perm(hi32, lo32, 0x05040100u);  // [hi0,hi1]
          L.u[rr] = __builtin_amdgcn_perm(hi32, lo32, 0x07060302u);  // [lo0,lo1]
        }
        ah[c] = H.v;
        al[c] = L.v;
      }
      if (__all(ok)) break;
      __builtin_amdgcn_s_sleep(1);
    }

    // prefetch next step's token + XV gate values (independent of h)
    float xrN, xzN, xnN;
    {
      int tN = (t + 1 < Sp) ? (t + 1) : t;
      int tokN = toks[eb * Sp + tN];
      const float* xvpN = XV + (size_t)tokN * (3 * Hp) + ej;
      xrN = xvpN[0];
      xzN = xvpN[Hp];
      xnN = xvpN[2 * Hp];
    }

    f4v ar = {0.f, 0.f, 0.f, 0.f}, az = {0.f, 0.f, 0.f, 0.f}, an = {0.f, 0.f, 0.f, 0.f};
    #pragma unroll
    for (int c = 0; c < 8; ++c) {
      s8v b0 = *(const s8v*)(bhp[0] + c * 32);
      s8v b1 = *(const s8v*)(bhp[1] + c * 32);
      s8v b2 = *(const s8v*)(bhp[2] + c * 32);
      s8v l0 = *(const s8v*)(blp[0] + c * 32);
      s8v l1 = *(const s8v*)(blp[1] + c * 32);
      s8v l2 = *(const s8v*)(blp[2] + c * 32);
      ar = __builtin_amdgcn_mfma_f32_16x16x32_bf16(ah[c], b0, ar, 0, 0, 0);
      az = __builtin_amdgcn_mfma_f32_16x16x32_bf16(ah[c], b1, az, 0, 0, 0);
      an = __builtin_amdgcn_mfma_f32_16x16x32_bf16(ah[c], b2, an, 0, 0, 0);
      ar = __builtin_amdgcn_mfma_f32_16x16x32_bf16(al[c], b0, ar, 0, 0, 0);
      az = __builtin_amdgcn_mfma_f32_16x16x32_bf16(al[c], b1, az, 0, 0, 0);
      an = __builtin_amdgcn_mfma_f32_16x16x32_bf16(al[c], b2, an, 0, 0, 0);
      ar = __builtin_amdgcn_mfma_f32_16x16x32_bf16(ah[c], l0, ar, 0, 0, 0);
      az = __builtin_amdgcn_mfma_f32_16x16x32_bf16(ah[c], l1, az, 0, 0, 0);
      an = __builtin_amdgcn_mfma_f32_16x16x32_bf16(ah[c], l2, an, 0, 0, 0);
    }

    // cross-wave K reduction via LDS
    *(f4v*)&part[((0 * 4 + wv) * 64 + lane) * 4] = ar;
    *(f4v*)&part[((1 * 4 + wv) * 64 + lane) * 4] = az;
    *(f4v*)&part[((2 * 4 + wv) * 64 + lane) * 4] = an;
    __syncthreads();

    float sr = 0.f, sz = 0.f, sn = 0.f;
    #pragma unroll
    for (int w = 0; w < 4; ++w) {
      sr += part[((0 * 4 + w) * 64 + elane) * 4 + er];
      sz += part[((1 * 4 + w) * 64 + elane) * 4 + er];
      sn += part[((2 * 4 + w) * 64 + elane) * 4 + er];
    }

    float rg = 1.f / (1.f + expf(-(sr + xr)));
    float zg = 1.f / (1.f + expf(-(sz + xz)));
    float ng = tanhf(xn + rg * (sn + bhnv));
    float hnew = (1.f - zg) * ng + zg * holdR;

    unsigned short hi16 = f2bf(hnew);
    hst[0][erow][ecol] = hi16;
    hst[1][erow][ecol] = f2bf(hnew - bf2f(hi16));

    holdR = hnew;
    xr = xrN; xz = xzN; xn = xnN;

    __syncthreads();

    // publish: threads 0..127 -> one self-validating 8B record each;
    // threads 128..255 -> ysH history (plain NT, read post-kernel only)
    const unsigned tagW = (unsigned)(t & 3);
    if (tid < 128) {
      int r = tid >> 3, p = tid & 7;
      unsigned long long h0 = hst[0][r][2 * p];
      unsigned long long l0 = (hst[1][r][2 * p] & 0xFFFCu) | tagW;
      unsigned long long h1 = hst[0][r][2 * p + 1];
      unsigned long long l1 = (hst[1][r][2 * p + 1] & 0xFFFCu) | tagW;
      unsigned long long rec = h0 | (l0 << 16) | (h1 << 32) | (l1 << 48);
      __hip_atomic_store(hxW + (size_t)(mb * 16 + r) * 512 + jb * 8 + p, rec,
                         __ATOMIC_RELAXED, __HIP_MEMORY_SCOPE_AGENT);
    } else {
      int t2 = tid - 128;
      int r = t2 >> 3, p = t2 & 7;
      unsigned dw = (unsigned)hst[0][r][2 * p] | ((unsigned)hst[0][r][2 * p + 1] << 16);
      __builtin_nontemporal_store(dw,
          (unsigned*)(ysH + (size_t)(t + 1) * BH + (size_t)(mb * 16 + r) * Hp + jb * 16 + 2 * p));
    }
    // no barrier: next iteration's retry loop enforces the data dependency
  }
}

// ---------------------------------------------------------------- fused MFMA output denses
__global__ __launch_bounds__(256, 1) void dense_kernel(
    const unsigned short* __restrict__ ysH,   // [(S+1)][B][H] bf16 hi; rows 1..S = h_t
    const unsigned short* __restrict__ WhbH, const unsigned short* __restrict__ WhbL,
    const float* __restrict__ bh,
    const unsigned short* __restrict__ WobH, const unsigned short* __restrict__ WobL,
    const float* __restrict__ bo,
    float* __restrict__ out) {
  __shared__ unsigned short aHi[32 * 16 * 4 * 8];    // [kc][m][kq][8] = 32 KB
  __shared__ unsigned short hidBf[32 * 16 * 4 * 8];  // same layout, 32 KB

  const int tid = threadIdx.x;
  const int wv = tid >> 6, lane = tid & 63;
  const int col = lane & 15, kq = lane >> 4;
  const int r0 = blockIdx.x * 16;
  const int bq = r0 / Sp, s0 = r0 % Sp;   // S%16==0: bq constant in tile

  for (int i = tid; i < 16 * 128; i += 256) {
    int m = i >> 7, c8 = i & 127;
    int kc = c8 >> 2, kqi = c8 & 3;
    const uint4* src = (const uint4*)(ysH + ((size_t)(s0 + m + 1) * Bp + bq) * Hp) + c8;
    *(uint4*)&aHi[((kc * 16 + m) * 4 + kqi) * 8] = *src;
  }
  __syncthreads();

  f4v acc[16];
  #pragma unroll
  for (int nt = 0; nt < 16; ++nt) acc[nt] = (f4v){0.f, 0.f, 0.f, 0.f};
  for (int kc = 0; kc < 32; ++kc) {
    s8v a = *(const s8v*)&aHi[(kc * 64 + col * 4 + kq) * 8];
    const size_t koff = (size_t)kc * 32 + kq * 8;
    #pragma unroll
    for (int nt = 0; nt < 16; ++nt) {
      int n = wv * 256 + nt * 16 + col;
      s8v bHi = *(const s8v*)(WhbH + (size_t)n * Hp + koff);
      s8v bLo = *(const s8v*)(WhbL + (size_t)n * Hp + koff);
      acc[nt] = __builtin_amdgcn_mfma_f32_16x16x32_bf16(a, bHi, acc[nt], 0, 0, 0);
      acc[nt] = __builtin_amdgcn_mfma_f32_16x16x32_bf16(a, bLo, acc[nt], 0, 0, 0);
    }
  }
  #pragma unroll
  for (int nt = 0; nt < 16; ++nt) {
    int n = wv * 256 + nt * 16 + col;
    float bias = bh[n];
    int kc = n >> 5, kqi = (n >> 3) & 3, ii = n & 7;
    #pragma unroll
    for (int r = 0; r < 4; ++r) {
      int m = kq * 4 + r;
      hidBf[((kc * 16 + m) * 4 + kqi) * 8 + ii] = f2bf(acc[nt][r] + bias);
    }
  }
  __syncthreads();

  f4v lacc[2];
  lacc[0] = (f4v){0.f, 0.f, 0.f, 0.f};
  lacc[1] = (f4v){0.f, 0.f, 0.f, 0.f};
  for (int kc = 0; kc < 32; ++kc) {
    s8v a = *(const s8v*)&hidBf[(kc * 64 + col * 4 + kq) * 8];
    const size_t koff = (size_t)kc * 32 + kq * 8;
    #pragma unroll
    for (int ot = 0; ot < 2; ++ot) {
      int o = (wv * 2 + ot) * 16 + col;
      s8v bHi = *(const s8v*)(WobH + (size_t)o * Hp + koff);
      s8v bLo = *(const s8v*)(WobL + (size_t)o * Hp + koff);
      lacc[ot] = __builtin_amdgcn_mfma_f32_16x16x32_bf16(a, bHi, lacc[ot], 0, 0, 0);
      lacc[ot] = __builtin_amdgcn_mfma_f32_16x16x32_bf16(a, bLo, lacc[ot], 0, 0, 0);
    }
  }
  float* lo = out + (size_t)Bp * Hp;
  #pragma unroll
  for (int ot = 0; ot < 2; ++ot) {
    int o = (wv * 2 + ot) * 16 + col;
    float bias = bo[o];
    #pragma unroll
    for (int r = 0; r < 4; ++r) {
      int m = kq * 4 + r;
      lo[(size_t)(r0 + m) * Op + o] = lacc[ot][r] + bias;
    }
  }
}

// ---------------------------------------------------------------- carry out (hi + exchange lo)
__global__ void carry_kernel(const unsigned short* __restrict__ ysH,
                             const unsigned long long* __restrict__ hx,
                             float* __restrict__ out) {
  int i = blockIdx.x * 256 + threadIdx.x;   // b*Hp + j
  int b = i >> 10, j = i & 1023;
  // h_{511} lives in hx slot (511&1)=1
  unsigned long long rec = hx[(BH / 2) + (size_t)b * 512 + (j >> 1)];
  unsigned short lo16 = (unsigned short)((rec >> (16 + 32 * (j & 1))) & 0xFFFCu);
  out[i] = bf2f(ysH[(size_t)Sp * BH + i]) + bf2f(lo16);
}

extern "C" void kernel_launch(void* const* d_in, const int* in_sizes, int n_in,
                              void* d_out, int out_size, void* d_ws, size_t ws_size,
                              hipStream_t stream) {
  const int*   toks = (const int*)  d_in[0];
  const float* carry= (const float*)d_in[1];
  const float* emb  = (const float*)d_in[2];
  const float* Wir  = (const float*)d_in[3];
  const float* bir  = (const float*)d_in[4];
  const float* Whr  = (const float*)d_in[5];
  const float* Wiz  = (const float*)d_in[6];
  const float* biz  = (const float*)d_in[7];
  const float* Whz  = (const float*)d_in[8];
  const float* Win  = (const float*)d_in[9];
  const float* bin_ = (const float*)d_in[10];
  const float* Whn  = (const float*)d_in[11];
  const float* bhn  = (const float*)d_in[12];
  const float* Wh   = (const float*)d_in[13];
  const float* bh   = (const float*)d_in[14];
  const float* Wo   = (const float*)d_in[15];
  const float* bo   = (const float*)d_in[16];
  float* out = (float*)d_out;

  if (ws_size < WS_FLOATS * sizeof(float)) return;

  float* ws = (float*)d_ws;
  float* XV = ws + WS_XV;
  unsigned short* WhiP = (unsigned short*)(ws + WS_WHI);
  unsigned short* WloP = (unsigned short*)(ws + WS_WLO);
  unsigned short* ysH  = (unsigned short*)(ws + WS_YSH);
  unsigned long long* hx = (unsigned long long*)(ws + WS_HX);
  unsigned short* WhbH = (unsigned short*)(ws + WS_WHBH);
  unsigned short* WhbL = (unsigned short*)(ws + WS_WHBL);
  unsigned short* WobH = (unsigned short*)(ws + WS_WOBH);
  unsigned short* WobL = (unsigned short*)(ws + WS_WOBL);

  // preps
  xv_kernel<<<dim3(12, Vp), 256, 0, stream>>>(emb, Wir, bir, Wiz, biz, Win, bin_, XV);
  wpack_kernel<<<dim3(Hp / 32, Hp / 32, 3), dim3(32, 8), 0, stream>>>(Whr, Whz, Whn, WhiP, WloP);
  tsplit_kernel<<<dim3(Hp / 32, Hp / 32), dim3(32, 8), 0, stream>>>(Wh, Hp, Hp, WhbH, WhbL);
  tsplit_kernel<<<dim3(Hp / 32, Op / 32), dim3(32, 8), 0, stream>>>(Wo, Hp, Op, WobH, WobL);
  h0_kernel<<<(BH / 2) / 256, 256, 0, stream>>>(carry, hx);

  // persistent MFMA scan — PLAIN launch (dataflow-synced; co-residency by
  // capacity: 256 blocks, >=1 block/CU guaranteed by __launch_bounds__(256,1))
  gru_scan<<<dim3(256), dim3(256), 0, stream>>>(carry, ysH, WhiP, WloP,
                                                XV, toks, bhn, hx);

  // outputs
  carry_kernel<<<BH / 256, 256, 0, stream>>>(ysH, hx, out);
  dense_kernel<<<(Bp * Sp) / 16, 256, 0, stream>>>(ysH, WhbH, WhbL, bh, WobH, WobL, bo, out);
}

// Round 11
// 4849.356 us; speedup vs baseline: 1.5030x; 1.0411x over previous
//
#include <hip/hip_runtime.h>
#include <math.h>

#define Bp 64
#define Sp 512
#define Ep 128
#define Hp 1024
#define Vp 128
#define Op 128
#define BH (Bp * Hp)

typedef short s8v __attribute__((ext_vector_type(8)));
typedef float f4v __attribute__((ext_vector_type(4)));

// ws layout (float units):
//   XV   : Vp*3*Hp floats      x-side projections per vocab id (incl. input biases)
//   Whi  : 3*Hp*Hp ushort      scan bf16 hi weights, row = ((j>>4)*3+g)*16+(j&15), k-contig
//   Wlo  : 3*Hp*Hp ushort      scan bf16 lo residuals, same layout
//   ysH  : (Sp+1)*BH ushort    bf16 hi of h history; row 0 = h_init, row t+1 = h_t
//   hloP : 2*BH ushort         bf16 lo of h, ping-pong (read slot t&1, write (t+1)&1)
//   WhbH/WhbL : Hp*Hp ushort   dense Wh bf16 hi/lo, [n][k] k-contig
//   WobH/WobL : Op*Hp ushort   dense Wo bf16 hi/lo, [o][k] k-contig
//   flg  : 256 uints           flags[mb*64+jb] = last published step+1
#define WS_XV    0
#define WS_WHI   (WS_XV + Vp*3*Hp)
#define WS_WLO   (WS_WHI + (3*Hp*Hp)/2)
#define WS_YSH   (WS_WLO + (3*Hp*Hp)/2)
#define WS_HLOP  (WS_YSH + ((size_t)(Sp+1)*BH)/2)
#define WS_WHBH  (WS_HLOP + (2*BH)/2)
#define WS_WHBL  (WS_WHBH + (Hp*Hp)/2)
#define WS_WOBH  (WS_WHBL + (Hp*Hp)/2)
#define WS_WOBL  (WS_WOBH + (Op*Hp)/2)
#define WS_FLG   (WS_WOBL + (Op*Hp)/2)
#define WS_FLOATS (WS_FLG + 256)

__device__ __forceinline__ unsigned short f2bf(float x) {
  union { float f; unsigned u; } v; v.f = x;
  unsigned r = v.u + 0x7fffu + ((v.u >> 16) & 1u);   // RNE
  return (unsigned short)(r >> 16);
}
__device__ __forceinline__ float bf2f(unsigned short h) {
  union { unsigned u; float f; } v; v.u = ((unsigned)h) << 16;
  return v.f;
}

// agent-coherent 16B load as two 8B relaxed atomics (sc1 — reads the coherence
// point; immune to stale per-XCD L2)
__device__ __forceinline__ s8v ald16(const unsigned short* p) {
  union { unsigned long long q[2]; s8v v; } u;
  const unsigned long long* qp = (const unsigned long long*)p;
  u.q[0] = __hip_atomic_load(qp,     __ATOMIC_RELAXED, __HIP_MEMORY_SCOPE_AGENT);
  u.q[1] = __hip_atomic_load(qp + 1, __ATOMIC_RELAXED, __HIP_MEMORY_SCOPE_AGENT);
  return u.v;
}
__device__ __forceinline__ void ast8(unsigned short* p, unsigned long long v) {
  __hip_atomic_store((unsigned long long*)p, v, __ATOMIC_RELAXED, __HIP_MEMORY_SCOPE_AGENT);
}

// ---------------------------------------------------------------- XV precompute
__global__ __launch_bounds__(256) void xv_kernel(
    const float* __restrict__ emb,
    const float* __restrict__ Wir, const float* __restrict__ bir,
    const float* __restrict__ Wiz, const float* __restrict__ biz,
    const float* __restrict__ Win, const float* __restrict__ bin_,
    float* __restrict__ XV) {
  int n = blockIdx.x * 256 + threadIdx.x;   // 0..3071
  int v = blockIdx.y;                        // 0..127
  int g = n >> 10;
  int j = n & (Hp - 1);
  const float* W = (g == 0) ? Wir : ((g == 1) ? Wiz : Win);
  const float* bias = (g == 0) ? bir : ((g == 1) ? biz : bin_);
  float acc = bias[j];
  const float* ev = emb + (size_t)v * Ep;
  for (int e = 0; e < Ep; ++e) acc += ev[e] * W[(size_t)e * Hp + j];
  XV[(size_t)v * (3 * Hp) + n] = acc;
}

// ---------------------------------------------------------------- scan weight pack (bf16 hi/lo)
__global__ void wpack_kernel(const float* __restrict__ Whr,
                             const float* __restrict__ Whz,
                             const float* __restrict__ Whn,
                             unsigned short* __restrict__ Whi,
                             unsigned short* __restrict__ Wlo) {
  __shared__ float tile[32][33];
  int g = blockIdx.z;
  const float* src = (g == 0) ? Whr : ((g == 1) ? Whz : Whn);
  int kb = blockIdx.x * 32;
  int jb32 = blockIdx.y * 32;
  int tx = threadIdx.x, ty = threadIdx.y;  // 32 x 8
  #pragma unroll
  for (int i = 0; i < 4; ++i)
    tile[ty + 8 * i][tx] = src[(size_t)(kb + ty + 8 * i) * Hp + (jb32 + tx)];
  __syncthreads();
  #pragma unroll
  for (int i = 0; i < 4; ++i) {
    int jl = ty + 8 * i;
    int j = jb32 + jl;
    int dstRow = ((j >> 4) * 3 + g) * 16 + (j & 15);
    float w = tile[tx][jl];
    unsigned short hi = f2bf(w);
    Whi[(size_t)dstRow * Hp + kb + tx] = hi;
    Wlo[(size_t)dstRow * Hp + kb + tx] = f2bf(w - bf2f(hi));
  }
}

// ---------------------------------------------------------------- generic transpose+split
__global__ void tsplit_kernel(const float* __restrict__ src, int K, int N,
                              unsigned short* __restrict__ dhi,
                              unsigned short* __restrict__ dlo) {
  __shared__ float tile[32][33];
  int kb = blockIdx.x * 32, nb = blockIdx.y * 32;
  int tx = threadIdx.x, ty = threadIdx.y;  // 32 x 8
  #pragma unroll
  for (int i = 0; i < 4; ++i)
    tile[ty + 8 * i][tx] = src[(size_t)(kb + ty + 8 * i) * N + nb + tx];
  __syncthreads();
  #pragma unroll
  for (int i = 0; i < 4; ++i) {
    int nl = ty + 8 * i;
    float w = tile[tx][nl];
    unsigned short hi = f2bf(w);
    dhi[(size_t)(nb + nl) * K + kb + tx] = hi;
    dlo[(size_t)(nb + nl) * K + kb + tx] = f2bf(w - bf2f(hi));
  }
}

// ---------------------------------------------------------------- h0 -> bf16 hi/lo ; zero flags
__global__ void h0_kernel(const float* __restrict__ carry,
                          unsigned short* __restrict__ ysH,
                          unsigned short* __restrict__ hloP,
                          unsigned* __restrict__ flg) {
  int i = blockIdx.x * 256 + threadIdx.x;
  float h = carry[i];
  unsigned short hi = f2bf(h);
  ysH[i] = hi;                    // history row 0 (read at t=0)
  hloP[i] = f2bf(h - bf2f(hi));   // slot 0 (read slot = t&1 at t=0)
  if (i < 256) flg[i] = 0u;
}

// ---------------------------------------------------------------- persistent MFMA GRU scan
// 256 blocks x 256 threads, PLAIN launch. Co-residency by capacity
// (__launch_bounds__(256,1): >=1 block/CU; 256 blocks <= 256 CUs), so spin
// waits always resolve regardless of dispatch order (G16-safe).
// mb = blk&3 (16-batch group), jb = blk>>2 (16 cols) — r6 mapping (best L2
// weight residency measured). Sync per group of 64: producer stores its own
// flag word (contention-free, no RMW); consumer polls all 64 flags with ONE
// coalesced load/lane + __all. No cache-wide fences; h planes + flags use
// agent-scope relaxed atomics (sc1); weights/XV/tokens normal cached loads.
__global__ __launch_bounds__(256, 1) void gru_scan(
    const float* __restrict__ carry,
    unsigned short* __restrict__ ysH,
    const unsigned short* __restrict__ Whi,
    const unsigned short* __restrict__ Wlo,
    const float* __restrict__ XV,
    const int* __restrict__ toks,
    const float* __restrict__ bhn,
    unsigned short* __restrict__ hloP,
    unsigned* __restrict__ flg) {
  __shared__ float part[3 * 4 * 64 * 4];    // [g][wave][lane][reg] = 12 KB
  __shared__ unsigned short hst[2][16][16]; // staged h tile (hi, lo), 1 KB

  const int tid = threadIdx.x;
  const int wv = tid >> 6, lane = tid & 63;
  const int mb = blockIdx.x & 3, jb = blockIdx.x >> 2;
  const int col = lane & 15, kq = lane >> 4;

  const int kbase = wv * 256 + kq * 8;
  const unsigned short* bhp[3];
  const unsigned short* blp[3];
  #pragma unroll
  for (int g = 0; g < 3; ++g) {
    const size_t rowoff = ((size_t)(jb * 3 + g) * 16 + col) * Hp + kbase;
    bhp[g] = Whi + rowoff;
    blp[g] = Wlo + rowoff;
  }

  // epilogue mapping: thread -> one output element (16x16 tile)
  const int erow = tid >> 4, ecol = tid & 15;
  const int eb = mb * 16 + erow;
  const int ej = jb * 16 + ecol;
  const int elane = (erow >> 2) * 16 + ecol;
  const int er = erow & 3;
  const float bhnv = bhn[ej];

  const size_t aBase = (size_t)(mb * 16 + col) * Hp + kbase;
  const size_t eOff = (size_t)eb * Hp + ej;

  float holdR = carry[eOff];
  int tok0 = toks[eb * Sp + 0];
  const float* xvp0 = XV + (size_t)tok0 * (3 * Hp) + ej;
  float xr = xvp0[0], xz = xvp0[Hp], xn = xvp0[2 * Hp];

  // store mapping: threads 0..127 -> one 8-B chunk (plane, row, quad)
  const int splane = tid >> 6;             // 0=hi, 1=lo (threads 0..127)
  const int srow = (tid >> 2) & 15;
  const int squad = tid & 3;
  const size_t sOff = (size_t)(mb * 16 + srow) * Hp + jb * 16 + squad * 4;

  const unsigned* fp = flg + mb * 64 + lane;   // one flag per lane covers all 64 jb

  for (int t = 0; t < Sp; ++t) {
    const unsigned short* hhiR = ysH + (size_t)t * BH;          // history row t
    const unsigned short* hloR = hloP + (size_t)(t & 1) * BH;
    unsigned short* hhiW = ysH + (size_t)(t + 1) * BH;
    unsigned short* hloW = hloP + (size_t)((t + 1) & 1) * BH;

    // ---- wait for h(t-1): coalesced 64-flag poll (1 load/lane/round) ----
    if (t > 0) {
      while (true) {
        unsigned f = __hip_atomic_load(fp, __ATOMIC_RELAXED, __HIP_MEMORY_SCOPE_AGENT);
        if (__all((int)(f >= (unsigned)t))) break;
        __builtin_amdgcn_s_sleep(1);
      }
    }

    // A fragments (agent-coherent; the only wait-dependent loads)
    s8v ah[8], al[8];
    #pragma unroll
    for (int c = 0; c < 8; ++c) {
      ah[c] = ald16(hhiR + aBase + (size_t)c * 32);
      al[c] = ald16(hloR + aBase + (size_t)c * 32);
    }

    // prefetch next step's token + XV gate values (independent of h)
    float xrN, xzN, xnN;
    {
      int tN = (t + 1 < Sp) ? (t + 1) : t;
      int tokN = toks[eb * Sp + tN];
      const float* xvpN = XV + (size_t)tokN * (3 * Hp) + ej;
      xrN = xvpN[0];
      xzN = xvpN[Hp];
      xnN = xvpN[2 * Hp];
    }

    f4v ar = {0.f, 0.f, 0.f, 0.f}, az = {0.f, 0.f, 0.f, 0.f}, an = {0.f, 0.f, 0.f, 0.f};
    #pragma unroll
    for (int c = 0; c < 8; ++c) {
      s8v b0 = *(const s8v*)(bhp[0] + c * 32);
      s8v b1 = *(const s8v*)(bhp[1] + c * 32);
      s8v b2 = *(const s8v*)(bhp[2] + c * 32);
      s8v l0 = *(const s8v*)(blp[0] + c * 32);
      s8v l1 = *(const s8v*)(blp[1] + c * 32);
      s8v l2 = *(const s8v*)(blp[2] + c * 32);
      ar = __builtin_amdgcn_mfma_f32_16x16x32_bf16(ah[c], b0, ar, 0, 0, 0);
      az = __builtin_amdgcn_mfma_f32_16x16x32_bf16(ah[c], b1, az, 0, 0, 0);
      an = __builtin_amdgcn_mfma_f32_16x16x32_bf16(ah[c], b2, an, 0, 0, 0);
      ar = __builtin_amdgcn_mfma_f32_16x16x32_bf16(al[c], b0, ar, 0, 0, 0);
      az = __builtin_amdgcn_mfma_f32_16x16x32_bf16(al[c], b1, az, 0, 0, 0);
      an = __builtin_amdgcn_mfma_f32_16x16x32_bf16(al[c], b2, an, 0, 0, 0);
      ar = __builtin_amdgcn_mfma_f32_16x16x32_bf16(ah[c], l0, ar, 0, 0, 0);
      az = __builtin_amdgcn_mfma_f32_16x16x32_bf16(ah[c], l1, az, 0, 0, 0);
      an = __builtin_amdgcn_mfma_f32_16x16x32_bf16(ah[c], l2, an, 0, 0, 0);
    }

    // cross-wave K reduction via LDS
    *(f4v*)&part[((0 * 4 + wv) * 64 + lane) * 4] = ar;
    *(f4v*)&part[((1 * 4 + wv) * 64 + lane) * 4] = az;
    *(f4v*)&part[((2 * 4 + wv) * 64 + lane) * 4] = an;
    __syncthreads();

    float sr = 0.f, sz = 0.f, sn = 0.f;
    #pragma unroll
    for (int w = 0; w < 4; ++w) {
      sr += part[((0 * 4 + w) * 64 + elane) * 4 + er];
      sz += part[((1 * 4 + w) * 64 + elane) * 4 + er];
      sn += part[((2 * 4 + w) * 64 + elane) * 4 + er];
    }

    float rg = 1.f / (1.f + expf(-(sr + xr)));
    float zg = 1.f / (1.f + expf(-(sz + xz)));
    float ng = tanhf(xn + rg * (sn + bhnv));
    float hnew = (1.f - zg) * ng + zg * holdR;

    unsigned short hi16 = f2bf(hnew);
    hst[0][erow][ecol] = hi16;
    hst[1][erow][ecol] = f2bf(hnew - bf2f(hi16));

    holdR = hnew;
    xr = xrN; xz = xzN; xn = xnN;

    __syncthreads();
    // vectorized agent-coherent h stores (threads 0..127, 8 B each);
    // hi-plane goes straight into the ysH history row t+1.
    if (tid < 128) {
      unsigned long long v = *(const unsigned long long*)&hst[splane][srow][squad * 4];
      ast8((splane ? hloW : hhiW) + sOff, v);
    }

    // drain own stores, then publish flag (contention-free store, no RMW)
    __threadfence_block();
    __syncthreads();
    if (tid == 0)
      __hip_atomic_store(flg + mb * 64 + jb, (unsigned)(t + 1),
                         __ATOMIC_RELAXED, __HIP_MEMORY_SCOPE_AGENT);
  }
}

// ---------------------------------------------------------------- fused MFMA output denses
__global__ __launch_bounds__(256, 1) void dense_kernel(
    const unsigned short* __restrict__ ysH,   // [(S+1)][B][H] bf16 hi; rows 1..S = h_t
    const unsigned short* __restrict__ WhbH, const unsigned short* __restrict__ WhbL,
    const float* __restrict__ bh,
    const unsigned short* __restrict__ WobH, const unsigned short* __restrict__ WobL,
    const float* __restrict__ bo,
    float* __restrict__ out) {
  __shared__ unsigned short aHi[32 * 16 * 4 * 8];    // [kc][m][kq][8] = 32 KB
  __shared__ unsigned short hidBf[32 * 16 * 4 * 8];  // same layout, 32 KB

  const int tid = threadIdx.x;
  const int wv = tid >> 6, lane = tid & 63;
  const int col = lane & 15, kq = lane >> 4;
  const int r0 = blockIdx.x * 16;
  const int bq = r0 / Sp, s0 = r0 % Sp;   // S%16==0: bq constant in tile

  for (int i = tid; i < 16 * 128; i += 256) {
    int m = i >> 7, c8 = i & 127;
    int kc = c8 >> 2, kqi = c8 & 3;
    const uint4* src = (const uint4*)(ysH + ((size_t)(s0 + m + 1) * Bp + bq) * Hp) + c8;
    *(uint4*)&aHi[((kc * 16 + m) * 4 + kqi) * 8] = *src;
  }
  __syncthreads();

  f4v acc[16];
  #pragma unroll
  for (int nt = 0; nt < 16; ++nt) acc[nt] = (f4v){0.f, 0.f, 0.f, 0.f};
  for (int kc = 0; kc < 32; ++kc) {
    s8v a = *(const s8v*)&aHi[(kc * 64 + col * 4 + kq) * 8];
    const size_t koff = (size_t)kc * 32 + kq * 8;
    #pragma unroll
    for (int nt = 0; nt < 16; ++nt) {
      int n = wv * 256 + nt * 16 + col;
      s8v bHi = *(const s8v*)(WhbH + (size_t)n * Hp + koff);
      s8v bLo = *(const s8v*)(WhbL + (size_t)n * Hp + koff);
      acc[nt] = __builtin_amdgcn_mfma_f32_16x16x32_bf16(a, bHi, acc[nt], 0, 0, 0);
      acc[nt] = __builtin_amdgcn_mfma_f32_16x16x32_bf16(a, bLo, acc[nt], 0, 0, 0);
    }
  }
  #pragma unroll
  for (int nt = 0; nt < 16; ++nt) {
    int n = wv * 256 + nt * 16 + col;
    float bias = bh[n];
    int kc = n >> 5, kqi = (n >> 3) & 3, ii = n & 7;
    #pragma unroll
    for (int r = 0; r < 4; ++r) {
      int m = kq * 4 + r;
      hidBf[((kc * 16 + m) * 4 + kqi) * 8 + ii] = f2bf(acc[nt][r] + bias);
    }
  }
  __syncthreads();

  f4v lacc[2];
  lacc[0] = (f4v){0.f, 0.f, 0.f, 0.f};
  lacc[1] = (f4v){0.f, 0.f, 0.f, 0.f};
  for (int kc = 0; kc < 32; ++kc) {
    s8v a = *(const s8v*)&hidBf[(kc * 64 + col * 4 + kq) * 8];
    const size_t koff = (size_t)kc * 32 + kq * 8;
    #pragma unroll
    for (int ot = 0; ot < 2; ++ot) {
      int o = (wv * 2 + ot) * 16 + col;
      s8v bHi = *(const s8v*)(WobH + (size_t)o * Hp + koff);
      s8v bLo = *(const s8v*)(WobL + (size_t)o * Hp + koff);
      lacc[ot] = __builtin_amdgcn_mfma_f32_16x16x32_bf16(a, bHi, lacc[ot], 0, 0, 0);
      lacc[ot] = __builtin_amdgcn_mfma_f32_16x16x32_bf16(a, bLo, lacc[ot], 0, 0, 0);
    }
  }
  float* lo = out + (size_t)Bp * Hp;
  #pragma unroll
  for (int ot = 0; ot < 2; ++ot) {
    int o = (wv * 2 + ot) * 16 + col;
    float bias = bo[o];
    #pragma unroll
    for (int r = 0; r < 4; ++r) {
      int m = kq * 4 + r;
      lo[(size_t)(r0 + m) * Op + o] = lacc[ot][r] + bias;
    }
  }
}

// ---------------------------------------------------------------- carry out (hi + lo reconstruct)
__global__ void carry_kernel(const unsigned short* __restrict__ ysH,
                             const unsigned short* __restrict__ hloP,
                             float* __restrict__ out) {
  int i = blockIdx.x * 256 + threadIdx.x;
  // h_511: hi in ysH row Sp; lo written at t=511 to slot (511+1)&1 = 0
  out[i] = bf2f(ysH[(size_t)Sp * BH + i]) + bf2f(hloP[i]);
}

extern "C" void kernel_launch(void* const* d_in, const int* in_sizes, int n_in,
                              void* d_out, int out_size, void* d_ws, size_t ws_size,
                              hipStream_t stream) {
  const int*   toks = (const int*)  d_in[0];
  const float* carry= (const float*)d_in[1];
  const float* emb  = (const float*)d_in[2];
  const float* Wir  = (const float*)d_in[3];
  const float* bir  = (const float*)d_in[4];
  const float* Whr  = (const float*)d_in[5];
  const float* Wiz  = (const float*)d_in[6];
  const float* biz  = (const float*)d_in[7];
  const float* Whz  = (const float*)d_in[8];
  const float* Win  = (const float*)d_in[9];
  const float* bin_ = (const float*)d_in[10];
  const float* Whn  = (const float*)d_in[11];
  const float* bhn  = (const float*)d_in[12];
  const float* Wh   = (const float*)d_in[13];
  const float* bh   = (const float*)d_in[14];
  const float* Wo   = (const float*)d_in[15];
  const float* bo   = (const float*)d_in[16];
  float* out = (float*)d_out;

  if (ws_size < WS_FLOATS * sizeof(float)) return;

  float* ws = (float*)d_ws;
  float* XV = ws + WS_XV;
  unsigned short* WhiP = (unsigned short*)(ws + WS_WHI);
  unsigned short* WloP = (unsigned short*)(ws + WS_WLO);
  unsigned short* ysH  = (unsigned short*)(ws + WS_YSH);
  unsigned short* hloP = (unsigned short*)(ws + WS_HLOP);
  unsigned short* WhbH = (unsigned short*)(ws + WS_WHBH);
  unsigned short* WhbL = (unsigned short*)(ws + WS_WHBL);
  unsigned short* WobH = (unsigned short*)(ws + WS_WOBH);
  unsigned short* WobL = (unsigned short*)(ws + WS_WOBL);
  unsigned* flg = (unsigned*)(ws + WS_FLG);

  // preps
  xv_kernel<<<dim3(12, Vp), 256, 0, stream>>>(emb, Wir, bir, Wiz, biz, Win, bin_, XV);
  wpack_kernel<<<dim3(Hp / 32, Hp / 32, 3), dim3(32, 8), 0, stream>>>(Whr, Whz, Whn, WhiP, WloP);
  tsplit_kernel<<<dim3(Hp / 32, Hp / 32), dim3(32, 8), 0, stream>>>(Wh, Hp, Hp, WhbH, WhbL);
  tsplit_kernel<<<dim3(Hp / 32, Op / 32), dim3(32, 8), 0, stream>>>(Wo, Hp, Op, WobH, WobL);
  h0_kernel<<<BH / 256, 256, 0, stream>>>(carry, ysH, hloP, flg);

  // persistent MFMA scan — PLAIN launch, flag-store/poll sync
  gru_scan<<<dim3(256), dim3(256), 0, stream>>>(carry, ysH, WhiP, WloP,
                                                XV, toks, bhn, hloP, flg);

  // outputs
  carry_kernel<<<BH / 256, 256, 0, stream>>>(ysH, hloP, out);
  dense_kernel<<<(Bp * Sp) / 16, 256, 0, stream>>>(ysH, WhbH, WhbL, bh, WobH, WobL, bo, out);
}